// Round 3
// baseline (574.036 us; speedup 1.0000x reference)
//
#include <hip/hip_runtime.h>
#include <hip/hip_bf16.h>

#define EPS 1e-5f

typedef __bf16 bf16x8 __attribute__((ext_vector_type(8)));
typedef float f32x4 __attribute__((ext_vector_type(4)));

// lds dest is WAVE-UNIFORM base; HW scatters lane i -> base + 16*i bytes
__device__ __forceinline__ void async_load16(const __bf16* g, __bf16* lds_base) {
  __builtin_amdgcn_global_load_lds(
      (const __attribute__((address_space(1))) unsigned int*)g,
      (__attribute__((address_space(3))) unsigned int*)lds_base, 16, 0, 0);
}

// ---- workspace layout (total 49,220,608 B) ---------------------------------
// xpadH : [8][30][30][512] bf16   @ 0          (7,372,800 B)
// t1pad : [16][58][58][256] bf16  @ 7,372,800  (27,557,888 B)
// wb    : [25][512][512] bf16     @ 34,930,688 (13,107,200 B)
// w2b   : [9][256][256] bf16      @ 48,037,888 (1,179,648 B)
// biasA : 512 f32                 @ 49,217,536
// bias2 : 256 f32                 @ 49,219,584

// ---------------- zero xpadH + t1pad (contiguous span) ----------------------
__global__ void zero_kernel(uint4* __restrict__ p, int n4) {
  int i = blockIdx.x * 256 + threadIdx.x;
  if (i < n4) p[i] = (uint4){0u, 0u, 0u, 0u};
}

// ---------------- weight prep: fold BN scale, convert to bf16 [tap][co][ci] --
// 131,072 threads for conv1+sc (one per (co<256, ci<512) pair, writes both
// wb slots), then 65,536 for conv2. FIX(R2): was tid<262144 -> co up to 511,
// 13 MB OOB read of w1/wsc -> memory fault.
__global__ void prep_kernel(const float* __restrict__ w1, const float* __restrict__ g1,
                            const float* __restrict__ b1, const float* __restrict__ m1,
                            const float* __restrict__ v1,
                            const float* __restrict__ wsc, const float* __restrict__ gs,
                            const float* __restrict__ bs, const float* __restrict__ ms,
                            const float* __restrict__ vs,
                            const float* __restrict__ w2, const float* __restrict__ g2,
                            const float* __restrict__ b2, const float* __restrict__ m2,
                            const float* __restrict__ v2,
                            __bf16* __restrict__ wb, __bf16* __restrict__ w2b,
                            float* __restrict__ biasA, float* __restrict__ bias2) {
  int tid = blockIdx.x * 256 + threadIdx.x;
  if (tid < 768) {
    int c = tid & 255;
    if (tid < 256)      biasA[c]       = b1[c] - m1[c] * (g1[c] * rsqrtf(v1[c] + EPS));
    else if (tid < 512) biasA[256 + c] = bs[c] - ms[c] * (gs[c] * rsqrtf(vs[c] + EPS));
    else                bias2[c]       = b2[c] - m2[c] * (g2[c] * rsqrtf(v2[c] + EPS));
  }
  if (tid < 131072) {
    int co = tid >> 9, ci = tid & 511;          // co in [0,256), ci in [0,512)
    float s1 = g1[co] * rsqrtf(v1[co] + EPS);
    float ss = gs[co] * rsqrtf(vs[co] + EPS);
    const float* p1 = w1 + (co * 512 + ci) * 25;
    const float* ps = wsc + (co * 512 + ci) * 25;
#pragma unroll
    for (int t = 0; t < 25; t++) {
      wb[(t * 512 + co) * 512 + ci]       = (__bf16)(p1[t] * s1);
      wb[(t * 512 + 256 + co) * 512 + ci] = (__bf16)(ps[t] * ss);
    }
  } else if (tid < 196608) {
    int t2 = tid - 131072;                      // < 65536
    int co = t2 >> 8, ci = t2 & 255;
    float s2 = g2[co] * rsqrtf(v2[co] + EPS);
    const float* p2 = w2 + (co * 256 + ci) * 9;
#pragma unroll
    for (int t = 0; t < 9; t++) w2b[(t * 256 + co) * 256 + ci] = (__bf16)(p2[t] * s2);
  }
}

// ------- x (NCHW f32, batch half) -> xpadH (padded NHWC bf16 [8][30][30][512])
__global__ void transpose_kernel(const float* __restrict__ x, __bf16* __restrict__ xpadH,
                                 int bbase) {
  __shared__ __bf16 tile[64 * 65];
  const int hw0 = blockIdx.x * 64;
  const int ci0 = blockIdx.y * 64;
  const int bl = blockIdx.z;            // local batch in [0,8)
  const int bg = bl + bbase;            // global batch
  const int tid = threadIdx.x;
#pragma unroll
  for (int it = 0; it < 16; ++it) {
    int idx = tid + 256 * it;
    int row = idx >> 6, col = idx & 63;
    int hw = hw0 + col;
    float v = (hw < 784) ? x[(bg * 512 + ci0 + row) * 784 + hw] : 0.0f;
    tile[row * 65 + col] = (__bf16)v;
  }
  __syncthreads();
#pragma unroll
  for (int it = 0; it < 16; ++it) {
    int idx = tid + 256 * it;
    int orow = idx >> 6, ocol = idx & 63;
    int hw = hw0 + orow;
    if (hw < 784) {
      int h = hw / 28, w = hw % 28;
      xpadH[((bl * 30 + 1 + h) * 30 + 1 + w) * 512 + ci0 + ocol] = tile[ocol * 65 + orow];
    }
  }
}

// ---------------- Kernel A: conv1 + shortcut conv (parity-decomposed) -------
// Per quadrant q=(py,px): GEMM M=6272 (bl,28,28), N=512 (co 0-255: w1 -> t1pad;
// co 256-511: wsc -> sc, written fp32 into d_out at final NCHW position).
__global__ __launch_bounds__(256) void convA_kernel(
    const __bf16* __restrict__ xpadH, const __bf16* __restrict__ wb,
    const float* __restrict__ biasA, __bf16* __restrict__ t1pad,
    float* __restrict__ scout, int bbase) {
  __shared__ alignas(16) __bf16 lA[128 * 32];
  __shared__ alignas(16) __bf16 lB[128 * 32];
  const int tid = threadIdx.x;
  const int lane = tid & 63, wv = tid >> 6;
  const int mtile = blockIdx.x, ntile = blockIdx.y, q = blockIdx.z;
  const int py = q >> 1, px = q & 1;

  const int srow = wv * 32 + (lane >> 2);       // staged row (this lane's quarter)
  const int schunk = (lane & 3) * 8;            // k-chunk within 32
  int aoff0, aoff1;
  {
    int m = mtile * 128 + srow;                 // local m in [0,6272)
    int b = m / 784, r = m % 784, hy = r / 28, hx = r % 28;
    aoff0 = ((b * 30 + 1 + hy) * 30 + (1 + hx)) * 512 + schunk;
    m += 16; b = m / 784; r = m % 784; hy = r / 28; hx = r % 28;
    aoff1 = ((b * 30 + 1 + hy) * 30 + (1 + hx)) * 512 + schunk;
  }
  const int boff0 = (ntile * 128 + srow) * 512 + schunk;
  __bf16* lbA = lA + wv * 1024;                 // wave-uniform LDS bases
  __bf16* lbB = lB + wv * 1024;

  const int wm = (wv & 1) * 64, wn = (wv >> 1) * 64;
  const int fr = lane & 15, kh = lane >> 4;

  f32x4 acc[4][4];
#pragma unroll
  for (int i = 0; i < 4; i++)
#pragma unroll
    for (int j = 0; j < 4; j++) acc[i][j] = (f32x4){0.f, 0.f, 0.f, 0.f};

  const int nty = py ? 2 : 3, ntx = px ? 2 : 3;
  for (int ty = 0; ty < nty; ++ty) {
    const int ky = py ? (2 * ty + 1) : (2 * ty);
    const int dy = py ? ty : (ty - 1);
    for (int tx = 0; tx < ntx; ++tx) {
      const int kx = px ? (2 * tx + 1) : (2 * tx);
      const int dx = px ? tx : (tx - 1);
      const int adelta = (dy * 30 + dx) * 512;
      const int woff = (ky * 5 + kx) * 512 * 512;
      for (int k0 = 0; k0 < 512; k0 += 32) {
        __syncthreads();
        async_load16(xpadH + (aoff0 + adelta + k0), lbA);
        async_load16(xpadH + (aoff1 + adelta + k0), lbA + 512);
        async_load16(wb + (woff + boff0 + k0), lbB);
        async_load16(wb + (woff + boff0 + 16 * 512 + k0), lbB + 512);
        __syncthreads();
        bf16x8 af[4], bfr[4];
#pragma unroll
        for (int f = 0; f < 4; f++)
          af[f] = *(const bf16x8*)(lA + (wm + f * 16 + fr) * 32 + kh * 8);
#pragma unroll
        for (int f = 0; f < 4; f++)
          bfr[f] = *(const bf16x8*)(lB + (wn + f * 16 + fr) * 32 + kh * 8);
#pragma unroll
        for (int i = 0; i < 4; i++)
#pragma unroll
          for (int j = 0; j < 4; j++)
            acc[i][j] = __builtin_amdgcn_mfma_f32_16x16x32_bf16(af[i], bfr[j], acc[i][j], 0, 0, 0);
      }
    }
  }

  // epilogue: C/D layout col(n)=lane&15, row(m)=(lane>>4)*4+reg
  const bool isT1 = (ntile < 2);
  int obT1[16], obSC[16];
#pragma unroll
  for (int i = 0; i < 4; i++)
#pragma unroll
    for (int r = 0; r < 4; r++) {
      int m = mtile * 128 + wm + i * 16 + kh * 4 + r;
      int bl = m / 784, rr = m % 784, hy = rr / 28, hx = rr % 28;
      int bg = bl + bbase;
      int oy = 2 * hy + py, ox = 2 * hx + px;
      obT1[i * 4 + r] = ((bg * 58 + 1 + oy) * 58 + (1 + ox)) * 256;
      obSC[i * 4 + r] = bg * 256 * 3136 + oy * 56 + ox;   // + co*3136 later
    }
#pragma unroll
  for (int j = 0; j < 4; j++) {
    int co2 = ntile * 128 + wn + j * 16 + fr;
    float bv = biasA[co2];
    if (isT1) {
#pragma unroll
      for (int i = 0; i < 4; i++)
#pragma unroll
        for (int r = 0; r < 4; r++) {
          float v = fmaxf(acc[i][j][r] + bv, 0.0f);
          t1pad[obT1[i * 4 + r] + co2] = (__bf16)v;
        }
    } else {
      int coL = co2 - 256;
#pragma unroll
      for (int i = 0; i < 4; i++)
#pragma unroll
        for (int r = 0; r < 4; r++) {
          scout[obSC[i * 4 + r] + coL * 3136] = acc[i][j][r] + bv;
        }
    }
  }
}

// ---------------- Kernel B: 3x3 conv on t1, + bias2 + sc(d_out), relu -------
// GEMM: M=50176 (b,56,56), N=256, K=256*9. sc is read from d_out (written by
// convA) at the exact element this thread will overwrite: read-then-write in
// the same thread => race-free.
__global__ __launch_bounds__(256) void convB_kernel(
    const __bf16* __restrict__ t1pad, const __bf16* __restrict__ w2b,
    const float* __restrict__ bias2, float* out) {
  __shared__ alignas(16) __bf16 lA[128 * 32];
  __shared__ alignas(16) __bf16 lB[128 * 32];
  const int tid = threadIdx.x;
  const int lane = tid & 63, wv = tid >> 6;
  const int mtile = blockIdx.x, ntile = blockIdx.y;

  const int srow = wv * 32 + (lane >> 2);
  const int schunk = (lane & 3) * 8;
  int aoff0, aoff1;
  {
    int m = mtile * 128 + srow;
    int b = m / 3136, r = m % 3136, y = r / 56, x = r % 56;
    aoff0 = ((b * 58 + 1 + y) * 58 + (1 + x)) * 256 + schunk;
    m += 16; b = m / 3136; r = m % 3136; y = r / 56; x = r % 56;
    aoff1 = ((b * 58 + 1 + y) * 58 + (1 + x)) * 256 + schunk;
  }
  const int boff0 = (ntile * 128 + srow) * 256 + schunk;
  __bf16* lbA = lA + wv * 1024;
  __bf16* lbB = lB + wv * 1024;

  const int wm = (wv & 1) * 64, wn = (wv >> 1) * 64;
  const int fr = lane & 15, kh = lane >> 4;

  f32x4 acc[4][4];
#pragma unroll
  for (int i = 0; i < 4; i++)
#pragma unroll
    for (int j = 0; j < 4; j++) acc[i][j] = (f32x4){0.f, 0.f, 0.f, 0.f};

  for (int tap = 0; tap < 9; ++tap) {
    const int dy = tap / 3 - 1, dx = tap % 3 - 1;
    const int adelta = (dy * 58 + dx) * 256;
    const int woff = tap * 256 * 256;
    for (int k0 = 0; k0 < 256; k0 += 32) {
      __syncthreads();
      async_load16(t1pad + (aoff0 + adelta + k0), lbA);
      async_load16(t1pad + (aoff1 + adelta + k0), lbA + 512);
      async_load16(w2b + (woff + boff0 + k0), lbB);
      async_load16(w2b + (woff + boff0 + 16 * 256 + k0), lbB + 512);
      __syncthreads();
      bf16x8 af[4], bfr[4];
#pragma unroll
      for (int f = 0; f < 4; f++)
        af[f] = *(const bf16x8*)(lA + (wm + f * 16 + fr) * 32 + kh * 8);
#pragma unroll
      for (int f = 0; f < 4; f++)
        bfr[f] = *(const bf16x8*)(lB + (wn + f * 16 + fr) * 32 + kh * 8);
#pragma unroll
      for (int i = 0; i < 4; i++)
#pragma unroll
        for (int j = 0; j < 4; j++)
          acc[i][j] = __builtin_amdgcn_mfma_f32_16x16x32_bf16(af[i], bfr[j], acc[i][j], 0, 0, 0);
    }
  }

  // epilogue: v = relu(acc + bias2 + sc); float4 in/out of d_out (NCHW)
#pragma unroll
  for (int i = 0; i < 4; i++) {
    int m0 = mtile * 128 + wm + i * 16 + kh * 4;    // multiple of 4; 3136%4==0
    int b = m0 / 3136, r0 = m0 % 3136;              // so m0..m0+3 same image
#pragma unroll
    for (int j = 0; j < 4; j++) {
      int co = ntile * 128 + wn + j * 16 + fr;
      float bv = bias2[co];
      float* p = out + ((b * 256 + co) * 3136 + r0);
      f32x4 sc = *(const f32x4*)p;
      f32x4 v;
#pragma unroll
      for (int r = 0; r < 4; r++) v[r] = fmaxf(acc[i][j][r] + bv + sc[r], 0.0f);
      *(f32x4*)p = v;
    }
  }
}

// ---------------- launch -----------------------------------------------------
extern "C" void kernel_launch(void* const* d_in, const int* in_sizes, int n_in,
                              void* d_out, int out_size, void* d_ws, size_t ws_size,
                              hipStream_t stream) {
  const float* x   = (const float*)d_in[0];
  const float* w1  = (const float*)d_in[1];
  const float* g1  = (const float*)d_in[2];
  const float* b1  = (const float*)d_in[3];
  const float* m1  = (const float*)d_in[4];
  const float* v1  = (const float*)d_in[5];
  const float* w2  = (const float*)d_in[6];
  const float* g2  = (const float*)d_in[7];
  const float* b2  = (const float*)d_in[8];
  const float* m2  = (const float*)d_in[9];
  const float* v2  = (const float*)d_in[10];
  const float* wsc = (const float*)d_in[11];
  const float* gs  = (const float*)d_in[12];
  const float* bs  = (const float*)d_in[13];
  const float* ms  = (const float*)d_in[14];
  const float* vs  = (const float*)d_in[15];
  float* out = (float*)d_out;

  char* ws = (char*)d_ws;
  __bf16* xpadH = (__bf16*)(ws);                  // 7,372,800 B
  __bf16* t1pad = (__bf16*)(ws + 7372800);        // 27,557,888 B
  __bf16* wb    = (__bf16*)(ws + 34930688);       // 13,107,200 B
  __bf16* w2b   = (__bf16*)(ws + 48037888);       // 1,179,648 B
  float* biasA  = (float*)(ws + 49217536);        // 2,048 B
  float* bias2  = (float*)(ws + 49219584);        // 1,024 B
  // total 49,220,608 B

  // zero xpadH + t1pad (contiguous 34,930,688 B = 2,183,168 uint4)
  zero_kernel<<<dim3(8528), 256, 0, stream>>>((uint4*)ws, 2183168);
  prep_kernel<<<dim3(768), 256, 0, stream>>>(w1, g1, b1, m1, v1, wsc, gs, bs, ms, vs,
                                             w2, g2, b2, m2, v2, wb, w2b, biasA, bias2);
  // batch half 0
  transpose_kernel<<<dim3(13, 8, 8), 256, 0, stream>>>(x, xpadH, 0);
  convA_kernel<<<dim3(49, 4, 4), 256, 0, stream>>>(xpadH, wb, biasA, t1pad, out, 0);
  // batch half 1 (reuses xpadH; interior fully rewritten, halo still zero)
  transpose_kernel<<<dim3(13, 8, 8), 256, 0, stream>>>(x, xpadH, 8);
  convA_kernel<<<dim3(49, 4, 4), 256, 0, stream>>>(xpadH, wb, biasA, t1pad, out, 8);
  // conv2 + bias + sc + relu
  convB_kernel<<<dim3(392, 2), 256, 0, stream>>>(t1pad, w2b, bias2, out);
}

// Round 4
// 488.132 us; speedup vs baseline: 1.1760x; 1.1760x over previous
//
#include <hip/hip_runtime.h>
#include <hip/hip_bf16.h>

#define EPS 1e-5f

typedef __bf16 bf16x8 __attribute__((ext_vector_type(8)));
typedef float f32x4 __attribute__((ext_vector_type(4)));

// lds dest is WAVE-UNIFORM base; HW scatters lane i -> base + 16*i bytes
__device__ __forceinline__ void async_load16(const __bf16* g, __bf16* lds_base) {
  __builtin_amdgcn_global_load_lds(
      (const __attribute__((address_space(1))) unsigned int*)g,
      (__attribute__((address_space(3))) unsigned int*)lds_base, 16, 0, 0);
}

// ---- workspace layout (total 82,283,520 B; ws_size >= this, proven R0) -----
// xpad  : [16][30][30][512] bf16 @ 0          (14,745,600 B)
// t1pad : [16][58][58][256] bf16 @ 14,745,600 (27,557,888 B)
// wb    : [25][512][512] bf16    @ 42,303,488 (13,107,200 B)
// w2b   : [9][256][256] bf16     @ 55,410,688 (1,179,648 B)
// scb   : [16][56][56][256] bf16 @ 56,590,336 (25,690,112 B)
// biasA : 512 f32                @ 82,280,448
// bias2 : 256 f32                @ 82,282,496

// ---------------- zero xpad + t1pad (contiguous span) -----------------------
__global__ void zero_kernel(uint4* __restrict__ p, int n4) {
  int i = blockIdx.x * 256 + threadIdx.x;
  if (i < n4) p[i] = (uint4){0u, 0u, 0u, 0u};
}

// ---------------- weight prep: fold BN scale, convert to bf16 [tap][co][ci] --
__global__ void prep_kernel(const float* __restrict__ w1, const float* __restrict__ g1,
                            const float* __restrict__ b1, const float* __restrict__ m1,
                            const float* __restrict__ v1,
                            const float* __restrict__ wsc, const float* __restrict__ gs,
                            const float* __restrict__ bs, const float* __restrict__ ms,
                            const float* __restrict__ vs,
                            const float* __restrict__ w2, const float* __restrict__ g2,
                            const float* __restrict__ b2, const float* __restrict__ m2,
                            const float* __restrict__ v2,
                            __bf16* __restrict__ wb, __bf16* __restrict__ w2b,
                            float* __restrict__ biasA, float* __restrict__ bias2) {
  int tid = blockIdx.x * 256 + threadIdx.x;
  if (tid < 768) {
    int c = tid & 255;
    if (tid < 256)      biasA[c]       = b1[c] - m1[c] * (g1[c] * rsqrtf(v1[c] + EPS));
    else if (tid < 512) biasA[256 + c] = bs[c] - ms[c] * (gs[c] * rsqrtf(vs[c] + EPS));
    else                bias2[c]       = b2[c] - m2[c] * (g2[c] * rsqrtf(v2[c] + EPS));
  }
  if (tid < 131072) {
    int co = tid >> 9, ci = tid & 511;          // co in [0,256), ci in [0,512)
    float s1 = g1[co] * rsqrtf(v1[co] + EPS);
    float ss = gs[co] * rsqrtf(vs[co] + EPS);
    const float* p1 = w1 + (co * 512 + ci) * 25;
    const float* ps = wsc + (co * 512 + ci) * 25;
#pragma unroll
    for (int t = 0; t < 25; t++) {
      wb[(t * 512 + co) * 512 + ci]       = (__bf16)(p1[t] * s1);
      wb[(t * 512 + 256 + co) * 512 + ci] = (__bf16)(ps[t] * ss);
    }
  } else if (tid < 196608) {
    int t2 = tid - 131072;                      // < 65536
    int co = t2 >> 8, ci = t2 & 255;
    float s2 = g2[co] * rsqrtf(v2[co] + EPS);
    const float* p2 = w2 + (co * 256 + ci) * 9;
#pragma unroll
    for (int t = 0; t < 9; t++) w2b[(t * 256 + co) * 256 + ci] = (__bf16)(p2[t] * s2);
  }
}

// ------- x (NCHW f32) -> xpad (padded NHWC bf16 [16][30][30][512]) ----------
__global__ void transpose_kernel(const float* __restrict__ x, __bf16* __restrict__ xpad) {
  __shared__ __bf16 tile[64 * 65];
  const int hw0 = blockIdx.x * 64;
  const int ci0 = blockIdx.y * 64;
  const int b = blockIdx.z;
  const int tid = threadIdx.x;
#pragma unroll
  for (int it = 0; it < 16; ++it) {
    int idx = tid + 256 * it;
    int row = idx >> 6, col = idx & 63;
    int hw = hw0 + col;
    float v = (hw < 784) ? x[(b * 512 + ci0 + row) * 784 + hw] : 0.0f;
    tile[row * 65 + col] = (__bf16)v;
  }
  __syncthreads();
#pragma unroll
  for (int it = 0; it < 16; ++it) {
    int idx = tid + 256 * it;
    int orow = idx >> 6, ocol = idx & 63;
    int hw = hw0 + orow;
    if (hw < 784) {
      int h = hw / 28, w = hw % 28;
      xpad[((b * 30 + 1 + h) * 30 + 1 + w) * 512 + ci0 + ocol] = tile[ocol * 65 + orow];
    }
  }
}

// ---------------- Kernel A: conv1 + shortcut conv (parity-decomposed) -------
// Per quadrant q=(py,px): GEMM M=12544 (b,28,28), N=512 (co 0-255: w1 ->
// t1pad bf16 padded-NHWC; co 256-511: wsc -> scb bf16 NHWC).
__global__ __launch_bounds__(256) void convA_kernel(
    const __bf16* __restrict__ xpad, const __bf16* __restrict__ wb,
    const float* __restrict__ biasA, __bf16* __restrict__ t1pad,
    __bf16* __restrict__ scb) {
  __shared__ alignas(16) __bf16 lA[128 * 32];
  __shared__ alignas(16) __bf16 lB[128 * 32];
  const int tid = threadIdx.x;
  const int lane = tid & 63, wv = tid >> 6;
  const int mtile = blockIdx.x, ntile = blockIdx.y, q = blockIdx.z;
  const int py = q >> 1, px = q & 1;

  const int srow = wv * 32 + (lane >> 2);       // staged row (this lane's quarter)
  const int schunk = (lane & 3) * 8;            // k-chunk within 32
  int aoff0, aoff1;
  {
    int m = mtile * 128 + srow;                 // m in [0,12544)
    int b = m / 784, r = m % 784, hy = r / 28, hx = r % 28;
    aoff0 = ((b * 30 + 1 + hy) * 30 + (1 + hx)) * 512 + schunk;
    m += 16; b = m / 784; r = m % 784; hy = r / 28; hx = r % 28;
    aoff1 = ((b * 30 + 1 + hy) * 30 + (1 + hx)) * 512 + schunk;
  }
  const int boff0 = (ntile * 128 + srow) * 512 + schunk;
  __bf16* lbA = lA + wv * 1024;                 // wave-uniform LDS bases
  __bf16* lbB = lB + wv * 1024;

  const int wm = (wv & 1) * 64, wn = (wv >> 1) * 64;
  const int fr = lane & 15, kh = lane >> 4;

  f32x4 acc[4][4];
#pragma unroll
  for (int i = 0; i < 4; i++)
#pragma unroll
    for (int j = 0; j < 4; j++) acc[i][j] = (f32x4){0.f, 0.f, 0.f, 0.f};

  const int nty = py ? 2 : 3, ntx = px ? 2 : 3;
  for (int ty = 0; ty < nty; ++ty) {
    const int ky = py ? (2 * ty + 1) : (2 * ty);
    const int dy = py ? ty : (ty - 1);
    for (int tx = 0; tx < ntx; ++tx) {
      const int kx = px ? (2 * tx + 1) : (2 * tx);
      const int dx = px ? tx : (tx - 1);
      const int adelta = (dy * 30 + dx) * 512;
      const int woff = (ky * 5 + kx) * 512 * 512;
      for (int k0 = 0; k0 < 512; k0 += 32) {
        __syncthreads();
        async_load16(xpad + (aoff0 + adelta + k0), lbA);
        async_load16(xpad + (aoff1 + adelta + k0), lbA + 512);
        async_load16(wb + (woff + boff0 + k0), lbB);
        async_load16(wb + (woff + boff0 + 16 * 512 + k0), lbB + 512);
        __syncthreads();
        bf16x8 af[4], bfr[4];
#pragma unroll
        for (int f = 0; f < 4; f++)
          af[f] = *(const bf16x8*)(lA + (wm + f * 16 + fr) * 32 + kh * 8);
#pragma unroll
        for (int f = 0; f < 4; f++)
          bfr[f] = *(const bf16x8*)(lB + (wn + f * 16 + fr) * 32 + kh * 8);
#pragma unroll
        for (int i = 0; i < 4; i++)
#pragma unroll
          for (int j = 0; j < 4; j++)
            acc[i][j] = __builtin_amdgcn_mfma_f32_16x16x32_bf16(af[i], bfr[j], acc[i][j], 0, 0, 0);
      }
    }
  }

  // epilogue: C/D layout col(n)=lane&15, row(m)=(lane>>4)*4+reg
  const bool isT1 = (ntile < 2);
  int ob[16];
#pragma unroll
  for (int i = 0; i < 4; i++)
#pragma unroll
    for (int r = 0; r < 4; r++) {
      int m = mtile * 128 + wm + i * 16 + kh * 4 + r;
      int b = m / 784, rr = m % 784, hy = rr / 28, hx = rr % 28;
      int oy = 2 * hy + py, ox = 2 * hx + px;
      ob[i * 4 + r] = isT1 ? ((b * 58 + 1 + oy) * 58 + (1 + ox)) * 256
                           : ((b * 56 + oy) * 56 + ox) * 256;
    }
  __bf16* outp = isT1 ? t1pad : scb;
#pragma unroll
  for (int j = 0; j < 4; j++) {
    int co2 = ntile * 128 + wn + j * 16 + fr;
    float bv = biasA[co2];
    int coL = isT1 ? co2 : (co2 - 256);
#pragma unroll
    for (int i = 0; i < 4; i++)
#pragma unroll
      for (int r = 0; r < 4; r++) {
        float v = acc[i][j][r] + bv;
        if (isT1) v = fmaxf(v, 0.0f);
        outp[ob[i * 4 + r] + coL] = (__bf16)v;
      }
  }
}

// ---------------- Kernel B: 3x3 conv on t1, + bias2 + scb, relu -> NCHW out -
// GEMM: M=50176 (b,56,56), N=256, K=256*9.
__global__ __launch_bounds__(256) void convB_kernel(
    const __bf16* __restrict__ t1pad, const __bf16* __restrict__ w2b,
    const float* __restrict__ bias2, const __bf16* __restrict__ scb,
    float* __restrict__ out) {
  __shared__ alignas(16) __bf16 lA[128 * 32];
  __shared__ alignas(16) __bf16 lB[128 * 32];
  const int tid = threadIdx.x;
  const int lane = tid & 63, wv = tid >> 6;
  const int mtile = blockIdx.x, ntile = blockIdx.y;

  const int srow = wv * 32 + (lane >> 2);
  const int schunk = (lane & 3) * 8;
  int aoff0, aoff1;
  {
    int m = mtile * 128 + srow;
    int b = m / 3136, r = m % 3136, y = r / 56, x = r % 56;
    aoff0 = ((b * 58 + 1 + y) * 58 + (1 + x)) * 256 + schunk;
    m += 16; b = m / 3136; r = m % 3136; y = r / 56; x = r % 56;
    aoff1 = ((b * 58 + 1 + y) * 58 + (1 + x)) * 256 + schunk;
  }
  const int boff0 = (ntile * 128 + srow) * 256 + schunk;
  __bf16* lbA = lA + wv * 1024;
  __bf16* lbB = lB + wv * 1024;

  const int wm = (wv & 1) * 64, wn = (wv >> 1) * 64;
  const int fr = lane & 15, kh = lane >> 4;

  f32x4 acc[4][4];
#pragma unroll
  for (int i = 0; i < 4; i++)
#pragma unroll
    for (int j = 0; j < 4; j++) acc[i][j] = (f32x4){0.f, 0.f, 0.f, 0.f};

  for (int tap = 0; tap < 9; ++tap) {
    const int dy = tap / 3 - 1, dx = tap % 3 - 1;
    const int adelta = (dy * 58 + dx) * 256;
    const int woff = tap * 256 * 256;
    for (int k0 = 0; k0 < 256; k0 += 32) {
      __syncthreads();
      async_load16(t1pad + (aoff0 + adelta + k0), lbA);
      async_load16(t1pad + (aoff1 + adelta + k0), lbA + 512);
      async_load16(w2b + (woff + boff0 + k0), lbB);
      async_load16(w2b + (woff + boff0 + 16 * 256 + k0), lbB + 512);
      __syncthreads();
      bf16x8 af[4], bfr[4];
#pragma unroll
      for (int f = 0; f < 4; f++)
        af[f] = *(const bf16x8*)(lA + (wm + f * 16 + fr) * 32 + kh * 8);
#pragma unroll
      for (int f = 0; f < 4; f++)
        bfr[f] = *(const bf16x8*)(lB + (wn + f * 16 + fr) * 32 + kh * 8);
#pragma unroll
      for (int i = 0; i < 4; i++)
#pragma unroll
        for (int j = 0; j < 4; j++)
          acc[i][j] = __builtin_amdgcn_mfma_f32_16x16x32_bf16(af[i], bfr[j], acc[i][j], 0, 0, 0);
    }
  }

  // epilogue: v = relu(acc + bias2 + sc); float4 store to NCHW d_out
#pragma unroll
  for (int i = 0; i < 4; i++) {
    int m0 = mtile * 128 + wm + i * 16 + kh * 4;    // multiple of 4; 56%4==0
    int b = m0 / 3136, r0 = m0 % 3136;              // rows don't split a float4
#pragma unroll
    for (int j = 0; j < 4; j++) {
      int co = ntile * 128 + wn + j * 16 + fr;
      float bv = bias2[co];
      const __bf16* scp = scb + (b * 3136 + r0) * 256 + co;
      f32x4 v;
#pragma unroll
      for (int r = 0; r < 4; r++) {
        float t = acc[i][j][r] + bv + (float)scp[r * 256];
        v[r] = fmaxf(t, 0.0f);
      }
      *(f32x4*)(out + ((b * 256 + co) * 3136 + r0)) = v;
    }
  }
}

// ---------------- launch -----------------------------------------------------
extern "C" void kernel_launch(void* const* d_in, const int* in_sizes, int n_in,
                              void* d_out, int out_size, void* d_ws, size_t ws_size,
                              hipStream_t stream) {
  const float* x   = (const float*)d_in[0];
  const float* w1  = (const float*)d_in[1];
  const float* g1  = (const float*)d_in[2];
  const float* b1  = (const float*)d_in[3];
  const float* m1  = (const float*)d_in[4];
  const float* v1  = (const float*)d_in[5];
  const float* w2  = (const float*)d_in[6];
  const float* g2  = (const float*)d_in[7];
  const float* b2  = (const float*)d_in[8];
  const float* m2  = (const float*)d_in[9];
  const float* v2  = (const float*)d_in[10];
  const float* wsc = (const float*)d_in[11];
  const float* gs  = (const float*)d_in[12];
  const float* bs  = (const float*)d_in[13];
  const float* ms  = (const float*)d_in[14];
  const float* vs  = (const float*)d_in[15];
  float* out = (float*)d_out;

  char* ws = (char*)d_ws;
  __bf16* xpad  = (__bf16*)(ws);                  // 14,745,600 B
  __bf16* t1pad = (__bf16*)(ws + 14745600);       // 27,557,888 B
  __bf16* wb    = (__bf16*)(ws + 42303488);       // 13,107,200 B
  __bf16* w2b   = (__bf16*)(ws + 55410688);       // 1,179,648 B
  __bf16* scb   = (__bf16*)(ws + 56590336);       // 25,690,112 B
  float* biasA  = (float*)(ws + 82280448);        // 2,048 B
  float* bias2  = (float*)(ws + 82282496);        // 1,024 B
  // total 82,283,520 B (same as R0 layout, which ran -> ws_size is >= this)

  // zero xpad + t1pad (contiguous 42,303,488 B = 2,643,968 uint4)
  zero_kernel<<<dim3(10328), 256, 0, stream>>>((uint4*)ws, 2643968);
  prep_kernel<<<dim3(768), 256, 0, stream>>>(w1, g1, b1, m1, v1, wsc, gs, bs, ms, vs,
                                             w2, g2, b2, m2, v2, wb, w2b, biasA, bias2);
  transpose_kernel<<<dim3(13, 8, 16), 256, 0, stream>>>(x, xpad);
  // full batch, one dispatch: 1568 blocks (~6/CU resident)
  convA_kernel<<<dim3(98, 4, 4), 256, 0, stream>>>(xpad, wb, biasA, t1pad, scb);
  convB_kernel<<<dim3(392, 2), 256, 0, stream>>>(t1pad, w2b, bias2, scb, out);
}

// Round 5
// 440.679 us; speedup vs baseline: 1.3026x; 1.1077x over previous
//
#include <hip/hip_runtime.h>
#include <hip/hip_bf16.h>

#define EPS 1e-5f

typedef __bf16 bf16x8 __attribute__((ext_vector_type(8)));
typedef float f32x4 __attribute__((ext_vector_type(4)));

// lds dest is WAVE-UNIFORM base; HW scatters lane i -> base + 16*i bytes
__device__ __forceinline__ void async_load16(const __bf16* g, __bf16* lds_base) {
  __builtin_amdgcn_global_load_lds(
      (const __attribute__((address_space(1))) unsigned int*)g,
      (__attribute__((address_space(3))) unsigned int*)lds_base, 16, 0, 0);
}

// ---- workspace layout (total 82,283,520 B; ws_size >= this, proven R0) -----
// xpad  : [16][30][30][512] bf16 @ 0          (14,745,600 B)
// t1pad : [16][58][58][256] bf16 @ 14,745,600 (27,557,888 B)
// wb    : [25][512][512] bf16    @ 42,303,488 (13,107,200 B)
// w2b   : [9][256][256] bf16     @ 55,410,688 (1,179,648 B)
// scb   : [16][56][56][256] bf16 @ 56,590,336 (25,690,112 B)
// biasA : 512 f32                @ 82,280,448
// bias2 : 256 f32                @ 82,282,496

// LDS swizzle invariant (both conv kernels, row = 64 elems = 8 chunks of 16B):
//   LDS[row][slot] holds global k-chunk  slot ^ (row & 7)
// Staging: lane i of a load covering rows j*8..j*8+7 fetches global chunk
//   (i&7)^((i>>3)&7) -> lands at slot i&7 of row j*8+(i>>3).  (row&7)=(i>>3)&7.
// Read of global chunk gc for row r: slot = gc ^ (r&7); r&7 == fr&7 for all
//   fragment rows (wm/wn and f*16 are multiples of 8).
// Bank check: quarter-wave (fixed kh) addr = r*128 + slot*16; slot covers all
//   8 4-bank groups 2-way -> conflict-free (2-way is free, m136).

// ---------------- zero xpad + t1pad (contiguous span) -----------------------
__global__ void zero_kernel(uint4* __restrict__ p, int n4) {
  int i = blockIdx.x * 256 + threadIdx.x;
  if (i < n4) p[i] = (uint4){0u, 0u, 0u, 0u};
}

// ---------------- weight prep: fold BN scale, bf16 [tap][co][ci], coalesced -
__global__ void prep_kernel(const float* __restrict__ w1, const float* __restrict__ g1,
                            const float* __restrict__ b1, const float* __restrict__ m1,
                            const float* __restrict__ v1,
                            const float* __restrict__ wsc, const float* __restrict__ gs,
                            const float* __restrict__ bs, const float* __restrict__ ms,
                            const float* __restrict__ vs,
                            const float* __restrict__ w2, const float* __restrict__ g2,
                            const float* __restrict__ b2, const float* __restrict__ m2,
                            const float* __restrict__ v2,
                            __bf16* __restrict__ wb, __bf16* __restrict__ w2b,
                            float* __restrict__ biasA, float* __restrict__ bias2) {
  int tid = blockIdx.x * 256 + threadIdx.x;
  if (tid < 409600) {                        // 25 taps * 256 co * 64 ci-groups
    int ci0 = tid & 63;
    int rest = tid >> 6;                     // < 6400
    int co = rest & 255;
    int t = rest >> 8;                       // < 25
    float s1 = g1[co] * rsqrtf(v1[co] + EPS);
    float ss = gs[co] * rsqrtf(vs[co] + EPS);
    const float* p1 = w1 + (co * 512 + ci0 * 8) * 25 + t;
    const float* ps = wsc + (co * 512 + ci0 * 8) * 25 + t;
    bf16x8 a, s;
#pragma unroll
    for (int e = 0; e < 8; ++e) {
      a[e] = (__bf16)(p1[e * 25] * s1);
      s[e] = (__bf16)(ps[e * 25] * ss);
    }
    *(bf16x8*)(wb + (t * 512 + co) * 512 + ci0 * 8) = a;
    *(bf16x8*)(wb + (t * 512 + 256 + co) * 512 + ci0 * 8) = s;
  } else if (tid < 483328) {                 // 9 taps * 256 co * 32 ci-groups
    int t2 = tid - 409600;
    int ci0 = t2 & 31;
    int rest = t2 >> 5;                      // < 2304
    int co = rest & 255;
    int t = rest >> 8;                       // < 9
    float s2 = g2[co] * rsqrtf(v2[co] + EPS);
    const float* p2 = w2 + (co * 256 + ci0 * 8) * 9 + t;
    bf16x8 a;
#pragma unroll
    for (int e = 0; e < 8; ++e) a[e] = (__bf16)(p2[e * 9] * s2);
    *(bf16x8*)(w2b + (t * 256 + co) * 256 + ci0 * 8) = a;
  } else if (tid < 484096) {
    int c = tid - 483328;
    if (c < 256)      biasA[c] = b1[c] - m1[c] * (g1[c] * rsqrtf(v1[c] + EPS));
    else if (c < 512) biasA[c] = bs[c - 256] - ms[c - 256] * (gs[c - 256] * rsqrtf(vs[c - 256] + EPS));
    else              bias2[c - 512] = b2[c - 512] - m2[c - 512] * (g2[c - 512] * rsqrtf(v2[c - 512] + EPS));
  }
}

// ------- x (NCHW f32) -> xpad (padded NHWC bf16 [16][30][30][512]) ----------
__global__ void transpose_kernel(const float* __restrict__ x, __bf16* __restrict__ xpad) {
  __shared__ __bf16 tile[64 * 65];
  const int hw0 = blockIdx.x * 64;
  const int ci0 = blockIdx.y * 64;
  const int b = blockIdx.z;
  const int tid = threadIdx.x;
#pragma unroll
  for (int it = 0; it < 16; ++it) {
    int idx = tid + 256 * it;
    int row = idx >> 6, col = idx & 63;
    int hw = hw0 + col;
    float v = (hw < 784) ? x[(b * 512 + ci0 + row) * 784 + hw] : 0.0f;
    tile[row * 65 + col] = (__bf16)v;
  }
  __syncthreads();
#pragma unroll
  for (int it = 0; it < 16; ++it) {
    int idx = tid + 256 * it;
    int orow = idx >> 6, ocol = idx & 63;
    int hw = hw0 + orow;
    if (hw < 784) {
      int h = hw / 28, w = hw % 28;
      xpad[((b * 30 + 1 + h) * 30 + 1 + w) * 512 + ci0 + ocol] = tile[ocol * 65 + orow];
    }
  }
}

// ---------------- Kernel A: conv1 + shortcut conv (parity-decomposed) -------
// Per quadrant q=(py,px): GEMM M=12544 (b,28,28), N=512 (co 0-255: w1 ->
// t1pad bf16 padded-NHWC; co 256-511: wsc -> scb bf16 NHWC). BK=64, swizzled.
__global__ __launch_bounds__(256) void convA_kernel(
    const __bf16* __restrict__ xpad, const __bf16* __restrict__ wb,
    const float* __restrict__ biasA, __bf16* __restrict__ t1pad,
    __bf16* __restrict__ scb) {
  __shared__ alignas(16) __bf16 lA[128 * 64];
  __shared__ alignas(16) __bf16 lB[128 * 64];
  const int tid = threadIdx.x;
  const int lane = tid & 63, wv = tid >> 6;
  const int mtile = blockIdx.x, ntile = blockIdx.y, q = blockIdx.z;
  const int py = q >> 1, px = q & 1;

  const int lrow = lane >> 3;                  // 0..7: row within 8-row group
  const int g = ((lane & 7) ^ lrow) * 8;       // swizzled global chunk (elems)
  int aoffs[4], boffs[4];
#pragma unroll
  for (int j = 0; j < 4; ++j) {
    int m = mtile * 128 + wv * 32 + j * 8 + lrow;
    int b = m / 784, r = m % 784, hy = r / 28, hx = r % 28;
    aoffs[j] = ((b * 30 + 1 + hy) * 30 + (1 + hx)) * 512 + g;
    boffs[j] = (ntile * 128 + wv * 32 + j * 8 + lrow) * 512 + g;
  }
  __bf16* lbA = lA + wv * 32 * 64;             // wave-uniform LDS bases
  __bf16* lbB = lB + wv * 32 * 64;

  const int wm = (wv & 1) * 64, wn = (wv >> 1) * 64;
  const int fr = lane & 15, kh = lane >> 4;
  const int sw = (fr & 7);                     // read-side swizzle key

  f32x4 acc[4][4];
#pragma unroll
  for (int i = 0; i < 4; i++)
#pragma unroll
    for (int j = 0; j < 4; j++) acc[i][j] = (f32x4){0.f, 0.f, 0.f, 0.f};

  const int nty = py ? 2 : 3, ntx = px ? 2 : 3;
  for (int ty = 0; ty < nty; ++ty) {
    const int ky = py ? (2 * ty + 1) : (2 * ty);
    const int dy = py ? ty : (ty - 1);
    for (int tx = 0; tx < ntx; ++tx) {
      const int kx = px ? (2 * tx + 1) : (2 * tx);
      const int dx = px ? tx : (tx - 1);
      const int adelta = (dy * 30 + dx) * 512;
      const int woff = (ky * 5 + kx) * 512 * 512;
      for (int k0 = 0; k0 < 512; k0 += 64) {
        __syncthreads();
#pragma unroll
        for (int j = 0; j < 4; ++j) {
          async_load16(xpad + (aoffs[j] + adelta + k0), lbA + j * 512);
          async_load16(wb + (woff + boffs[j] + k0), lbB + j * 512);
        }
        __syncthreads();
#pragma unroll
        for (int kk = 0; kk < 2; ++kk) {
          const int slot = ((kk * 4 + kh) ^ sw) * 8;
          bf16x8 af[4], bfr[4];
#pragma unroll
          for (int f = 0; f < 4; f++)
            af[f] = *(const bf16x8*)(lA + (wm + f * 16 + fr) * 64 + slot);
#pragma unroll
          for (int f = 0; f < 4; f++)
            bfr[f] = *(const bf16x8*)(lB + (wn + f * 16 + fr) * 64 + slot);
#pragma unroll
          for (int i = 0; i < 4; i++)
#pragma unroll
            for (int j = 0; j < 4; j++)
              acc[i][j] = __builtin_amdgcn_mfma_f32_16x16x32_bf16(af[i], bfr[j], acc[i][j], 0, 0, 0);
        }
      }
    }
  }

  // epilogue: C/D layout col(n)=lane&15, row(m)=(lane>>4)*4+reg
  const bool isT1 = (ntile < 2);
  int ob[16];
#pragma unroll
  for (int i = 0; i < 4; i++)
#pragma unroll
    for (int r = 0; r < 4; r++) {
      int m = mtile * 128 + wm + i * 16 + kh * 4 + r;
      int b = m / 784, rr = m % 784, hy = rr / 28, hx = rr % 28;
      int oy = 2 * hy + py, ox = 2 * hx + px;
      ob[i * 4 + r] = isT1 ? ((b * 58 + 1 + oy) * 58 + (1 + ox)) * 256
                           : ((b * 56 + oy) * 56 + ox) * 256;
    }
  __bf16* outp = isT1 ? t1pad : scb;
#pragma unroll
  for (int j = 0; j < 4; j++) {
    int co2 = ntile * 128 + wn + j * 16 + fr;
    float bv = biasA[co2];
    int coL = isT1 ? co2 : (co2 - 256);
#pragma unroll
    for (int i = 0; i < 4; i++)
#pragma unroll
      for (int r = 0; r < 4; r++) {
        float v = acc[i][j][r] + bv;
        if (isT1) v = fmaxf(v, 0.0f);
        outp[ob[i * 4 + r] + coL] = (__bf16)v;
      }
  }
}

// ---------------- Kernel B: 3x3 conv on t1, + bias2 + scb, relu -> NCHW out -
// GEMM: M=50176 (b,56,56), N=256, K=256*9. BK=64, swizzled.
__global__ __launch_bounds__(256) void convB_kernel(
    const __bf16* __restrict__ t1pad, const __bf16* __restrict__ w2b,
    const float* __restrict__ bias2, const __bf16* __restrict__ scb,
    float* __restrict__ out) {
  __shared__ alignas(16) __bf16 lA[128 * 64];
  __shared__ alignas(16) __bf16 lB[128 * 64];
  const int tid = threadIdx.x;
  const int lane = tid & 63, wv = tid >> 6;
  const int mtile = blockIdx.x, ntile = blockIdx.y;

  const int lrow = lane >> 3;
  const int g = ((lane & 7) ^ lrow) * 8;
  int aoffs[4], boffs[4];
#pragma unroll
  for (int j = 0; j < 4; ++j) {
    int m = mtile * 128 + wv * 32 + j * 8 + lrow;
    int b = m / 3136, r = m % 3136, y = r / 56, x = r % 56;
    aoffs[j] = ((b * 58 + 1 + y) * 58 + (1 + x)) * 256 + g;
    boffs[j] = (ntile * 128 + wv * 32 + j * 8 + lrow) * 256 + g;
  }
  __bf16* lbA = lA + wv * 32 * 64;
  __bf16* lbB = lB + wv * 32 * 64;

  const int wm = (wv & 1) * 64, wn = (wv >> 1) * 64;
  const int fr = lane & 15, kh = lane >> 4;
  const int sw = (fr & 7);

  f32x4 acc[4][4];
#pragma unroll
  for (int i = 0; i < 4; i++)
#pragma unroll
    for (int j = 0; j < 4; j++) acc[i][j] = (f32x4){0.f, 0.f, 0.f, 0.f};

  for (int tap = 0; tap < 9; ++tap) {
    const int dy = tap / 3 - 1, dx = tap % 3 - 1;
    const int adelta = (dy * 58 + dx) * 256;
    const int woff = tap * 256 * 256;
    for (int k0 = 0; k0 < 256; k0 += 64) {
      __syncthreads();
#pragma unroll
      for (int j = 0; j < 4; ++j) {
        async_load16(t1pad + (aoffs[j] + adelta + k0), lbA + j * 512);
        async_load16(w2b + (woff + boffs[j] + k0), lbB + j * 512);
      }
      __syncthreads();
#pragma unroll
      for (int kk = 0; kk < 2; ++kk) {
        const int slot = ((kk * 4 + kh) ^ sw) * 8;
        bf16x8 af[4], bfr[4];
#pragma unroll
        for (int f = 0; f < 4; f++)
          af[f] = *(const bf16x8*)(lA + (wm + f * 16 + fr) * 64 + slot);
#pragma unroll
        for (int f = 0; f < 4; f++)
          bfr[f] = *(const bf16x8*)(lB + (wn + f * 16 + fr) * 64 + slot);
#pragma unroll
        for (int i = 0; i < 4; i++)
#pragma unroll
          for (int j = 0; j < 4; j++)
            acc[i][j] = __builtin_amdgcn_mfma_f32_16x16x32_bf16(af[i], bfr[j], acc[i][j], 0, 0, 0);
      }
    }
  }

  // epilogue: v = relu(acc + bias2 + sc); float4 store to NCHW d_out
#pragma unroll
  for (int i = 0; i < 4; i++) {
    int m0 = mtile * 128 + wm + i * 16 + kh * 4;    // multiple of 4; 56%4==0
    int b = m0 / 3136, r0 = m0 % 3136;              // rows don't split a float4
#pragma unroll
    for (int j = 0; j < 4; j++) {
      int co = ntile * 128 + wn + j * 16 + fr;
      float bv = bias2[co];
      const __bf16* scp = scb + (b * 3136 + r0) * 256 + co;
      f32x4 v;
#pragma unroll
      for (int r = 0; r < 4; r++) {
        float t = acc[i][j][r] + bv + (float)scp[r * 256];
        v[r] = fmaxf(t, 0.0f);
      }
      *(f32x4*)(out + ((b * 256 + co) * 3136 + r0)) = v;
    }
  }
}

// ---------------- launch -----------------------------------------------------
extern "C" void kernel_launch(void* const* d_in, const int* in_sizes, int n_in,
                              void* d_out, int out_size, void* d_ws, size_t ws_size,
                              hipStream_t stream) {
  const float* x   = (const float*)d_in[0];
  const float* w1  = (const float*)d_in[1];
  const float* g1  = (const float*)d_in[2];
  const float* b1  = (const float*)d_in[3];
  const float* m1  = (const float*)d_in[4];
  const float* v1  = (const float*)d_in[5];
  const float* w2  = (const float*)d_in[6];
  const float* g2  = (const float*)d_in[7];
  const float* b2  = (const float*)d_in[8];
  const float* m2  = (const float*)d_in[9];
  const float* v2  = (const float*)d_in[10];
  const float* wsc = (const float*)d_in[11];
  const float* gs  = (const float*)d_in[12];
  const float* bs  = (const float*)d_in[13];
  const float* ms  = (const float*)d_in[14];
  const float* vs  = (const float*)d_in[15];
  float* out = (float*)d_out;

  char* ws = (char*)d_ws;
  __bf16* xpad  = (__bf16*)(ws);                  // 14,745,600 B
  __bf16* t1pad = (__bf16*)(ws + 14745600);       // 27,557,888 B
  __bf16* wb    = (__bf16*)(ws + 42303488);       // 13,107,200 B
  __bf16* w2b   = (__bf16*)(ws + 55410688);       // 1,179,648 B
  __bf16* scb   = (__bf16*)(ws + 56590336);       // 25,690,112 B
  float* biasA  = (float*)(ws + 82280448);        // 2,048 B
  float* bias2  = (float*)(ws + 82282496);        // 1,024 B

  // zero xpad + t1pad (contiguous 42,303,488 B = 2,643,968 uint4)
  zero_kernel<<<dim3(10328), 256, 0, stream>>>((uint4*)ws, 2643968);
  prep_kernel<<<dim3(1891), 256, 0, stream>>>(w1, g1, b1, m1, v1, wsc, gs, bs, ms, vs,
                                              w2, g2, b2, m2, v2, wb, w2b, biasA, bias2);
  transpose_kernel<<<dim3(13, 8, 16), 256, 0, stream>>>(x, xpad);
  convA_kernel<<<dim3(98, 4, 4), 256, 0, stream>>>(xpad, wb, biasA, t1pad, scb);
  convB_kernel<<<dim3(392, 2), 256, 0, stream>>>(t1pad, w2b, bias2, scb, out);
}